// Round 2
// baseline (498.023 us; speedup 1.0000x reference)
//
#include <hip/hip_runtime.h>

#define NEG_INF (-__builtin_huge_valf())

// Max-plus 5x5 dilation, fp32, NCHW (16,64,256,256), 'same' pad (2,2) with -inf.
// Block (64,4): lane tx covers 4 contiguous cols (4tx..4tx+3) -> every wave
// VMEM instruction is a contiguous 1KB access (16 cache lines, vs 32 for the
// R1 strided layout). Each thread: 8 output rows x 4 cols; 12 input rows.
__global__ __launch_bounds__(256)
void semiconv2d_dilate(const float* __restrict__ in,
                       const float* __restrict__ ker,
                       float* __restrict__ out) {
    const int tx = threadIdx.x;                      // 0..63
    const int ty = threadIdx.y;                      // 0..3
    const int c  = tx << 2;                          // base col, 0..252
    const int r0 = (blockIdx.x << 5) + (ty << 3);    // base output row
    const long long plane = blockIdx.y;              // b*64 + ch

    const float* __restrict__ pin  = in  + plane * 65536;
    float* __restrict__       pout = out + plane * 65536;

    float kk[25];
    #pragma unroll
    for (int t = 0; t < 25; ++t) kk[t] = ker[t];

    float acc[8][4];
    #pragma unroll
    for (int i = 0; i < 8; ++i)
        #pragma unroll
        for (int x = 0; x < 4; ++x) acc[i][x] = NEG_INF;

    // Input rows r0-2 .. r0+9 feed output rows r0 .. r0+7.
    #pragma unroll
    for (int j = 0; j < 12; ++j) {
        const int ir = r0 - 2 + j;
        // w[q] = input[ir][c - 4 + q], q in [0,12). Used: w[2..9] (cols c-2..c+5).
        float w[12];
        if (ir >= 0 && ir < 256) {                   // wave-uniform branch
            const float* rp = pin + (ir << 8) + c;
            if (tx > 0) {
                float4 a = *reinterpret_cast<const float4*>(rp - 4);
                w[0]=a.x; w[1]=a.y; w[2]=a.z; w[3]=a.w;
            } else { w[0]=NEG_INF; w[1]=NEG_INF; w[2]=NEG_INF; w[3]=NEG_INF; }
            float4 b = *reinterpret_cast<const float4*>(rp);
            w[4]=b.x; w[5]=b.y; w[6]=b.z; w[7]=b.w;
            if (tx < 63) {
                float4 d = *reinterpret_cast<const float4*>(rp + 4);
                w[8]=d.x; w[9]=d.y; w[10]=d.z; w[11]=d.w;
            } else { w[8]=NEG_INF; w[9]=NEG_INF; w[10]=NEG_INF; w[11]=NEG_INF; }
        } else {
            #pragma unroll
            for (int t = 0; t < 12; ++t) w[t] = NEG_INF;
        }

        // Input row ir contributes tap u = j - i to output row i (0<=u<5).
        #pragma unroll
        for (int i = 0; i < 8; ++i) {
            const int u = j - i;
            if (u >= 0 && u < 5) {                   // folds at compile time
                const float k0 = kk[u*5+0], k1 = kk[u*5+1], k2 = kk[u*5+2];
                const float k3 = kk[u*5+3], k4 = kk[u*5+4];
                #pragma unroll
                for (int x = 0; x < 4; ++x) {
                    // pairs -> v_max3_f32 fusion
                    float t0 = w[x+2] + k0;
                    float t1 = w[x+3] + k1;
                    acc[i][x] = fmaxf(acc[i][x], fmaxf(t0, t1));
                    float t2 = w[x+4] + k2;
                    float t3 = w[x+5] + k3;
                    acc[i][x] = fmaxf(acc[i][x], fmaxf(t2, t3));
                    acc[i][x] = fmaxf(acc[i][x], w[x+6] + k4);
                }
            }
        }
    }

    #pragma unroll
    for (int i = 0; i < 8; ++i) {
        float* op = pout + ((r0 + i) << 8) + c;
        *reinterpret_cast<float4*>(op) =
            make_float4(acc[i][0], acc[i][1], acc[i][2], acc[i][3]);
    }
}

extern "C" void kernel_launch(void* const* d_in, const int* in_sizes, int n_in,
                              void* d_out, int out_size, void* d_ws, size_t ws_size,
                              hipStream_t stream) {
    const float* in  = (const float*)d_in[0];   // (16,64,256,256) fp32
    const float* ker = (const float*)d_in[1];   // (5,5) fp32
    float* out = (float*)d_out;

    // 1024 planes of 256x256; each block: full 256-col width x 32 rows.
    dim3 grid(256 / 32, 16 * 64);
    dim3 block(64, 4);
    semiconv2d_dilate<<<grid, block, 0, stream>>>(in, ker, out);
}